// Round 1
// baseline (692.202 us; speedup 1.0000x reference)
//
#include <hip/hip_runtime.h>

#define NN 100000
#define NE 3200000
#define HC 16

__global__ __launch_bounds__(256) void k_deg(const int* __restrict__ dst,
                                             unsigned int* __restrict__ deg, int E) {
    int i = blockIdx.x * blockDim.x + threadIdx.x;
    if (i < E) atomicAdd(&deg[dst[i]], 1u);
}

__global__ __launch_bounds__(256) void k_node1(const float* __restrict__ x,
                                               const unsigned int* __restrict__ deg,
                                               float* __restrict__ dinv,
                                               float* __restrict__ p,
                                               float* __restrict__ t, int N) {
    int i = blockIdx.x * blockDim.x + threadIdx.x;
    if (i < N) {
        float d = (float)(deg[i] + 1u);   // +1 for self-loop
        float di = rsqrtf(d);
        dinv[i] = di;
        float pi = di * x[i];
        p[i] = pi;
        t[i] = pi;                        // self-loop contribution to layer-1 agg
    }
}

__global__ __launch_bounds__(256) void k_scatter1(const int* __restrict__ src,
                                                  const int* __restrict__ dst,
                                                  const float* __restrict__ p,
                                                  float* __restrict__ t, int E) {
    int i = blockIdx.x * blockDim.x + threadIdx.x;
    if (i < E) atomicAdd(&t[dst[i]], p[src[i]]);
}

__global__ __launch_bounds__(256) void k_node2(const float* __restrict__ dinv,
                                               const float* __restrict__ t,
                                               const float* __restrict__ W1,
                                               const float* __restrict__ b1,
                                               const float* __restrict__ W2,
                                               float2* __restrict__ g,
                                               float2* __restrict__ acc, int N) {
    int i = blockIdx.x * blockDim.x + threadIdx.x;
    if (i < N) {
        float di = dinv[i];
        float s = di * t[i];
        float g0 = 0.f, g1 = 0.f;
#pragma unroll
        for (int c = 0; c < HC; ++c) {
            float h = fmaxf(fmaf(s, W1[c], b1[c]), 0.f);   // relu(layer-1 out)
            g0 = fmaf(h, W2[2 * c], g0);
            g1 = fmaf(h, W2[2 * c + 1], g1);
        }
        float2 gv = make_float2(di * g0, di * g1);
        g[i] = gv;
        acc[i] = gv;   // self-loop contribution to layer-2 agg (acc == d_out)
    }
}

__global__ __launch_bounds__(256) void k_scatter2(const int* __restrict__ src,
                                                  const int* __restrict__ dst,
                                                  const float2* __restrict__ g,
                                                  float* __restrict__ acc, int E) {
    int i = blockIdx.x * blockDim.x + threadIdx.x;
    if (i < E) {
        int s = src[i], d = dst[i];
        float2 gv = g[s];
        atomicAdd(&acc[2 * d], gv.x);
        atomicAdd(&acc[2 * d + 1], gv.y);
    }
}

__global__ __launch_bounds__(256) void k_out(const float* __restrict__ dinv,
                                             const float* __restrict__ b2,
                                             float* __restrict__ out, int N) {
    int i = blockIdx.x * blockDim.x + threadIdx.x;
    if (i < N) {
        float di = dinv[i];
        out[2 * i]     = fmaf(di, out[2 * i],     b2[0]);
        out[2 * i + 1] = fmaf(di, out[2 * i + 1], b2[1]);
    }
}

extern "C" void kernel_launch(void* const* d_in, const int* in_sizes, int n_in,
                              void* d_out, int out_size, void* d_ws, size_t ws_size,
                              hipStream_t stream) {
    const float* x  = (const float*)d_in[0];
    const int* ei   = (const int*)d_in[1];
    const int* src  = ei;        // edge_index[0]
    const int* dst  = ei + NE;   // edge_index[1]
    const float* W1 = (const float*)d_in[2];
    const float* b1 = (const float*)d_in[3];
    const float* W2 = (const float*)d_in[4];
    const float* b2 = (const float*)d_in[5];
    float* out = (float*)d_out;

    // workspace carve-up (all fp32-sized slots)
    char* ws = (char*)d_ws;
    unsigned int* deg = (unsigned int*)ws;            // N u32
    float* dinv = (float*)(ws + 1 * sizeof(float) * NN);
    float* p    = (float*)(ws + 2 * sizeof(float) * NN);
    float* t    = (float*)(ws + 3 * sizeof(float) * NN);
    float2* g   = (float2*)(ws + 4 * sizeof(float) * NN);  // 2N floats

    const int BT = 256;
    const int gridE = (NE + BT - 1) / BT;
    const int gridN = (NN + BT - 1) / BT;

    hipMemsetAsync(deg, 0, NN * sizeof(unsigned int), stream);
    k_deg<<<gridE, BT, 0, stream>>>(dst, deg, NE);
    k_node1<<<gridN, BT, 0, stream>>>(x, deg, dinv, p, t, NN);
    k_scatter1<<<gridE, BT, 0, stream>>>(src, dst, p, t, NE);
    k_node2<<<gridN, BT, 0, stream>>>(dinv, t, W1, b1, W2, g, (float2*)out, NN);
    k_scatter2<<<gridE, BT, 0, stream>>>(src, dst, g, out, NE);
    k_out<<<gridN, BT, 0, stream>>>(dinv, b2, out, NN);
}

// Round 2
// 383.830 us; speedup vs baseline: 1.8034x; 1.8034x over previous
//
#include <hip/hip_runtime.h>

#define NN 100000
#define NE 3200000
#define HC 16

// ---------------- CSR-gather path ----------------

__global__ __launch_bounds__(256) void k_init_cursor(int* __restrict__ cursor, int pad, int N) {
    int i = blockIdx.x * blockDim.x + threadIdx.x;
    if (i < N) cursor[i] = i * pad;
}

__global__ __launch_bounds__(256) void k_fill(const int* __restrict__ src,
                                              const int* __restrict__ dst,
                                              int* __restrict__ cursor,
                                              int* __restrict__ csr,
                                              int pad, int E) {
    int i = blockIdx.x * blockDim.x + threadIdx.x;
    if (i < E) {
        int s = src[i], d = dst[i];
        int pos = atomicAdd(&cursor[d], 1);
        if (pos < (d + 1) * pad) csr[pos] = s;   // overflow guard (unreachable at pad>=96)
    }
}

__global__ __launch_bounds__(256) void k_node1(const float* __restrict__ x,
                                               const int* __restrict__ cursor,
                                               float* __restrict__ dinv,
                                               float* __restrict__ p,
                                               int pad, int N) {
    int i = blockIdx.x * blockDim.x + threadIdx.x;
    if (i < N) {
        int cnt = cursor[i] - i * pad;           // in-degree (without self-loop)
        float di = rsqrtf((float)(cnt + 1));
        dinv[i] = di;
        p[i] = di * x[i];
    }
}

// gather layer-1 + fused MLP (x@W1+b1 -> relu -> @W2), output g = dinv * (...)
__global__ __launch_bounds__(256) void k_l1(const int* __restrict__ cursor,
                                            const int* __restrict__ csr,
                                            const float* __restrict__ dinv,
                                            const float* __restrict__ p,
                                            const float* __restrict__ W1,
                                            const float* __restrict__ b1,
                                            const float* __restrict__ W2,
                                            float2* __restrict__ g,
                                            int pad, int N) {
    int i = blockIdx.x * blockDim.x + threadIdx.x;
    if (i >= N) return;
    int cnt = cursor[i] - i * pad;
    const int4* row = (const int4*)(csr + (size_t)i * pad);
    float acc = p[i];                            // self-loop
    int nvec = (cnt + 3) >> 2;
    for (int v = 0; v < nvec; ++v) {
        int4 c = row[v];
        int base = v * 4;
        if (base + 0 < cnt) acc += p[c.x];
        if (base + 1 < cnt) acc += p[c.y];
        if (base + 2 < cnt) acc += p[c.z];
        if (base + 3 < cnt) acc += p[c.w];
    }
    float di = dinv[i];
    float s = di * acc;                          // layer-1 pre-MLP scalar
    float g0 = 0.f, g1 = 0.f;
#pragma unroll
    for (int c = 0; c < HC; ++c) {
        float h = fmaxf(fmaf(s, W1[c], b1[c]), 0.f);
        g0 = fmaf(h, W2[2 * c], g0);
        g1 = fmaf(h, W2[2 * c + 1], g1);
    }
    g[i] = make_float2(di * g0, di * g1);
}

// gather layer-2 + epilogue
__global__ __launch_bounds__(256) void k_l2(const int* __restrict__ cursor,
                                            const int* __restrict__ csr,
                                            const float* __restrict__ dinv,
                                            const float2* __restrict__ g,
                                            const float* __restrict__ b2,
                                            float2* __restrict__ out,
                                            int pad, int N) {
    int i = blockIdx.x * blockDim.x + threadIdx.x;
    if (i >= N) return;
    int cnt = cursor[i] - i * pad;
    const int4* row = (const int4*)(csr + (size_t)i * pad);
    float2 me = g[i];
    float a0 = me.x, a1 = me.y;                  // self-loop
    int nvec = (cnt + 3) >> 2;
    for (int v = 0; v < nvec; ++v) {
        int4 c = row[v];
        int base = v * 4;
        if (base + 0 < cnt) { float2 t = g[c.x]; a0 += t.x; a1 += t.y; }
        if (base + 1 < cnt) { float2 t = g[c.y]; a0 += t.x; a1 += t.y; }
        if (base + 2 < cnt) { float2 t = g[c.z]; a0 += t.x; a1 += t.y; }
        if (base + 3 < cnt) { float2 t = g[c.w]; a0 += t.x; a1 += t.y; }
    }
    float di = dinv[i];
    out[i] = make_float2(fmaf(di, a0, b2[0]), fmaf(di, a1, b2[1]));
}

// ---------------- fallback: round-1 atomic-scatter path (small ws) ----------------

__global__ __launch_bounds__(256) void f_deg(const int* __restrict__ dst,
                                             unsigned int* __restrict__ deg, int E) {
    int i = blockIdx.x * blockDim.x + threadIdx.x;
    if (i < E) atomicAdd(&deg[dst[i]], 1u);
}
__global__ __launch_bounds__(256) void f_node1(const float* __restrict__ x,
                                               const unsigned int* __restrict__ deg,
                                               float* __restrict__ dinv, float* __restrict__ p,
                                               float* __restrict__ t, int N) {
    int i = blockIdx.x * blockDim.x + threadIdx.x;
    if (i < N) {
        float di = rsqrtf((float)(deg[i] + 1u));
        dinv[i] = di; float pi = di * x[i]; p[i] = pi; t[i] = pi;
    }
}
__global__ __launch_bounds__(256) void f_scatter1(const int* __restrict__ src,
                                                  const int* __restrict__ dst,
                                                  const float* __restrict__ p,
                                                  float* __restrict__ t, int E) {
    int i = blockIdx.x * blockDim.x + threadIdx.x;
    if (i < E) atomicAdd(&t[dst[i]], p[src[i]]);
}
__global__ __launch_bounds__(256) void f_node2(const float* __restrict__ dinv,
                                               const float* __restrict__ t,
                                               const float* __restrict__ W1,
                                               const float* __restrict__ b1,
                                               const float* __restrict__ W2,
                                               float2* __restrict__ g,
                                               float2* __restrict__ acc, int N) {
    int i = blockIdx.x * blockDim.x + threadIdx.x;
    if (i < N) {
        float di = dinv[i]; float s = di * t[i];
        float g0 = 0.f, g1 = 0.f;
#pragma unroll
        for (int c = 0; c < HC; ++c) {
            float h = fmaxf(fmaf(s, W1[c], b1[c]), 0.f);
            g0 = fmaf(h, W2[2 * c], g0); g1 = fmaf(h, W2[2 * c + 1], g1);
        }
        float2 gv = make_float2(di * g0, di * g1);
        g[i] = gv; acc[i] = gv;
    }
}
__global__ __launch_bounds__(256) void f_scatter2(const int* __restrict__ src,
                                                  const int* __restrict__ dst,
                                                  const float2* __restrict__ g,
                                                  float* __restrict__ acc, int E) {
    int i = blockIdx.x * blockDim.x + threadIdx.x;
    if (i < E) {
        int s = src[i], d = dst[i];
        float2 gv = g[s];
        atomicAdd(&acc[2 * d], gv.x);
        atomicAdd(&acc[2 * d + 1], gv.y);
    }
}
__global__ __launch_bounds__(256) void f_out(const float* __restrict__ dinv,
                                             const float* __restrict__ b2,
                                             float* __restrict__ out, int N) {
    int i = blockIdx.x * blockDim.x + threadIdx.x;
    if (i < N) {
        float di = dinv[i];
        out[2 * i]     = fmaf(di, out[2 * i],     b2[0]);
        out[2 * i + 1] = fmaf(di, out[2 * i + 1], b2[1]);
    }
}

extern "C" void kernel_launch(void* const* d_in, const int* in_sizes, int n_in,
                              void* d_out, int out_size, void* d_ws, size_t ws_size,
                              hipStream_t stream) {
    const float* x  = (const float*)d_in[0];
    const int* ei   = (const int*)d_in[1];
    const int* src  = ei;
    const int* dst  = ei + NE;
    const float* W1 = (const float*)d_in[2];
    const float* b1 = (const float*)d_in[3];
    const float* W2 = (const float*)d_in[4];
    const float* b2 = (const float*)d_in[5];
    float* out = (float*)d_out;

    const int BT = 256;
    const int gridE = (NE + BT - 1) / BT;
    const int gridN = (NN + BT - 1) / BT;

    // pick largest safe row pad that fits the workspace
    const size_t fixed = (size_t)NN * 4 * 4;  // cursor + dinv + p + g(2N floats)
    int pad = 0;
    if (ws_size >= fixed + (size_t)NN * 128 * 4) pad = 128;
    else if (ws_size >= fixed + (size_t)NN * 96 * 4) pad = 96;

    if (pad) {
        char* ws = (char*)d_ws;
        int*   cursor = (int*)ws;
        float* dinv   = (float*)(ws + 1 * sizeof(float) * NN);
        float* p      = (float*)(ws + 2 * sizeof(float) * NN);
        float2* g     = (float2*)(ws + 3 * sizeof(float) * NN);
        int*   csr    = (int*)(ws + 5 * sizeof(float) * NN);

        k_init_cursor<<<gridN, BT, 0, stream>>>(cursor, pad, NN);
        k_fill<<<gridE, BT, 0, stream>>>(src, dst, cursor, csr, pad, NE);
        k_node1<<<gridN, BT, 0, stream>>>(x, cursor, dinv, p, pad, NN);
        k_l1<<<gridN, BT, 0, stream>>>(cursor, csr, dinv, p, W1, b1, W2, g, pad, NN);
        k_l2<<<gridN, BT, 0, stream>>>(cursor, csr, dinv, g, b2, (float2*)out, pad, NN);
    } else {
        // fallback: atomic scatter (round-1 algorithm)
        char* ws = (char*)d_ws;
        unsigned int* deg = (unsigned int*)ws;
        float* dinv = (float*)(ws + 1 * sizeof(float) * NN);
        float* p    = (float*)(ws + 2 * sizeof(float) * NN);
        float* t    = (float*)(ws + 3 * sizeof(float) * NN);
        float2* g   = (float2*)(ws + 4 * sizeof(float) * NN);

        hipMemsetAsync(deg, 0, NN * sizeof(unsigned int), stream);
        f_deg<<<gridE, BT, 0, stream>>>(dst, deg, NE);
        f_node1<<<gridN, BT, 0, stream>>>(x, deg, dinv, p, t, NN);
        f_scatter1<<<gridE, BT, 0, stream>>>(src, dst, p, t, NE);
        f_node2<<<gridN, BT, 0, stream>>>(dinv, t, W1, b1, W2, g, (float2*)out, NN);
        f_scatter2<<<gridE, BT, 0, stream>>>(src, dst, g, out, NE);
        f_out<<<gridN, BT, 0, stream>>>(dinv, b2, out, NN);
    }
}

// Round 3
// 246.718 us; speedup vs baseline: 2.8056x; 1.5557x over previous
//
#include <hip/hip_runtime.h>

#define NN 100000
#define NE 3200000
#define HC 16

#define BKT_BITS 8
#define BKT_NODES 256                 // nodes per bucket
#define NB 391                        // ceil(NN / 256)
#define CHUNK 32768
#define NCH 98                        // ceil(NE / CHUNK)

// ---------- pass 1: bucket-bin the edges (no global atomics) ----------

__global__ __launch_bounds__(256) void k_hist(const int* __restrict__ dst,
                                              unsigned* __restrict__ H) {
    __shared__ unsigned h[NB];
    int tid = threadIdx.x;
    for (int j = tid; j < NB; j += 256) h[j] = 0;
    __syncthreads();
    int b0 = blockIdx.x * CHUNK;
    int e1 = min(b0 + CHUNK, NE);
    for (int i = b0 + tid; i < e1; i += 256)
        atomicAdd(&h[((unsigned)dst[i]) >> BKT_BITS], 1u);
    __syncthreads();
    for (int j = tid; j < NB; j += 256) H[(size_t)blockIdx.x * NB + j] = h[j];
}

__global__ __launch_bounds__(256) void k_colscan(const unsigned* __restrict__ H,
                                                 unsigned* __restrict__ Off,
                                                 unsigned* __restrict__ total) {
    int b = blockIdx.x * 256 + threadIdx.x;
    if (b >= NB) return;
    unsigned run = 0;
    for (int c = 0; c < NCH; ++c) {
        unsigned v = H[(size_t)c * NB + b];
        Off[(size_t)c * NB + b] = run;
        run += v;
    }
    total[b] = run;
}

__global__ __launch_bounds__(512) void k_base(const unsigned* __restrict__ total,
                                              unsigned* __restrict__ base) {
    __shared__ unsigned s[512];
    int t = threadIdx.x;
    unsigned v = (t < NB) ? total[t] : 0;
    s[t] = v;
    __syncthreads();
    for (int off = 1; off < 512; off <<= 1) {
        unsigned u = (t >= off) ? s[t - off] : 0;
        __syncthreads();
        s[t] += u;
        __syncthreads();
    }
    if (t < NB) base[t] = s[t] - v;   // exclusive prefix
}

__global__ __launch_bounds__(256) void k_place(const int* __restrict__ src,
                                               const int* __restrict__ dst,
                                               const unsigned* __restrict__ Off,
                                               const unsigned* __restrict__ base,
                                               unsigned* __restrict__ binned) {
    __shared__ unsigned cur[NB];
    int tid = threadIdx.x;
    for (int j = tid; j < NB; j += 256)
        cur[j] = base[j] + Off[(size_t)blockIdx.x * NB + j];
    __syncthreads();
    int b0 = blockIdx.x * CHUNK;
    int e1 = min(b0 + CHUNK, NE);
    for (int i = b0 + tid; i < e1; i += 256) {
        unsigned d = (unsigned)dst[i];
        unsigned s = (unsigned)src[i];
        unsigned bk = d >> BKT_BITS;
        unsigned pos = atomicAdd(&cur[bk], 1u);           // LDS atomic only
        binned[pos] = (s << BKT_BITS) | (d & (BKT_NODES - 1));
    }
}

// ---------- pass 2: per-bucket LDS aggregation ----------

__global__ __launch_bounds__(256) void k_degnode(const unsigned* __restrict__ binned,
                                                 const unsigned* __restrict__ base,
                                                 const unsigned* __restrict__ total,
                                                 const float* __restrict__ x,
                                                 float* __restrict__ dinv,
                                                 float* __restrict__ p) {
    __shared__ unsigned cnt[BKT_NODES];
    int tid = threadIdx.x;
    cnt[tid] = 0;
    __syncthreads();
    unsigned s0 = base[blockIdx.x], c0 = total[blockIdx.x];
    for (unsigned i = tid; i < c0; i += 256)
        atomicAdd(&cnt[binned[s0 + i] & (BKT_NODES - 1)], 1u);
    __syncthreads();
    int node = blockIdx.x * BKT_NODES + tid;
    if (node < NN) {
        float di = rsqrtf((float)(cnt[tid] + 1u));        // +1 self-loop
        dinv[node] = di;
        p[node] = di * x[node];
    }
}

__global__ __launch_bounds__(256) void k_agg1(const unsigned* __restrict__ binned,
                                              const unsigned* __restrict__ base,
                                              const unsigned* __restrict__ total,
                                              const float* __restrict__ dinv,
                                              const float* __restrict__ p,
                                              const float* __restrict__ W1,
                                              const float* __restrict__ b1,
                                              const float* __restrict__ W2,
                                              float2* __restrict__ g) {
    __shared__ float acc[BKT_NODES];
    int tid = threadIdx.x;
    acc[tid] = 0.f;
    __syncthreads();
    unsigned s0 = base[blockIdx.x], c0 = total[blockIdx.x];
    for (unsigned i = tid; i < c0; i += 256) {
        unsigned e = binned[s0 + i];
        atomicAdd(&acc[e & (BKT_NODES - 1)], p[e >> BKT_BITS]);
    }
    __syncthreads();
    int node = blockIdx.x * BKT_NODES + tid;
    if (node < NN) {
        float di = dinv[node];
        float s = di * (acc[tid] + p[node]);              // + self-loop
        float g0 = 0.f, g1 = 0.f;
#pragma unroll
        for (int c = 0; c < HC; ++c) {
            float h = fmaxf(fmaf(s, W1[c], b1[c]), 0.f);
            g0 = fmaf(h, W2[2 * c], g0);
            g1 = fmaf(h, W2[2 * c + 1], g1);
        }
        g[node] = make_float2(di * g0, di * g1);
    }
}

__global__ __launch_bounds__(256) void k_agg2(const unsigned* __restrict__ binned,
                                              const unsigned* __restrict__ base,
                                              const unsigned* __restrict__ total,
                                              const float* __restrict__ dinv,
                                              const float2* __restrict__ g,
                                              const float* __restrict__ b2,
                                              float2* __restrict__ out) {
    __shared__ float ax[BKT_NODES];
    __shared__ float ay[BKT_NODES];
    int tid = threadIdx.x;
    ax[tid] = 0.f; ay[tid] = 0.f;
    __syncthreads();
    unsigned s0 = base[blockIdx.x], c0 = total[blockIdx.x];
    for (unsigned i = tid; i < c0; i += 256) {
        unsigned e = binned[s0 + i];
        float2 v = g[e >> BKT_BITS];
        unsigned l = e & (BKT_NODES - 1);
        atomicAdd(&ax[l], v.x);
        atomicAdd(&ay[l], v.y);
    }
    __syncthreads();
    int node = blockIdx.x * BKT_NODES + tid;
    if (node < NN) {
        float di = dinv[node];
        float2 me = g[node];
        out[node] = make_float2(fmaf(di, ax[tid] + me.x, b2[0]),
                                fmaf(di, ay[tid] + me.y, b2[1]));
    }
}

// ---------- fallback: round-1 atomic-scatter path (small ws) ----------

__global__ __launch_bounds__(256) void f_deg(const int* __restrict__ dst,
                                             unsigned int* __restrict__ deg, int E) {
    int i = blockIdx.x * blockDim.x + threadIdx.x;
    if (i < E) atomicAdd(&deg[dst[i]], 1u);
}
__global__ __launch_bounds__(256) void f_node1(const float* __restrict__ x,
                                               const unsigned int* __restrict__ deg,
                                               float* __restrict__ dinv, float* __restrict__ p,
                                               float* __restrict__ t, int N) {
    int i = blockIdx.x * blockDim.x + threadIdx.x;
    if (i < N) {
        float di = rsqrtf((float)(deg[i] + 1u));
        dinv[i] = di; float pi = di * x[i]; p[i] = pi; t[i] = pi;
    }
}
__global__ __launch_bounds__(256) void f_scatter1(const int* __restrict__ src,
                                                  const int* __restrict__ dst,
                                                  const float* __restrict__ p,
                                                  float* __restrict__ t, int E) {
    int i = blockIdx.x * blockDim.x + threadIdx.x;
    if (i < E) atomicAdd(&t[dst[i]], p[src[i]]);
}
__global__ __launch_bounds__(256) void f_node2(const float* __restrict__ dinv,
                                               const float* __restrict__ t,
                                               const float* __restrict__ W1,
                                               const float* __restrict__ b1,
                                               const float* __restrict__ W2,
                                               float2* __restrict__ g,
                                               float2* __restrict__ acc, int N) {
    int i = blockIdx.x * blockDim.x + threadIdx.x;
    if (i < N) {
        float di = dinv[i]; float s = di * t[i];
        float g0 = 0.f, g1 = 0.f;
#pragma unroll
        for (int c = 0; c < HC; ++c) {
            float h = fmaxf(fmaf(s, W1[c], b1[c]), 0.f);
            g0 = fmaf(h, W2[2 * c], g0); g1 = fmaf(h, W2[2 * c + 1], g1);
        }
        float2 gv = make_float2(di * g0, di * g1);
        g[i] = gv; acc[i] = gv;
    }
}
__global__ __launch_bounds__(256) void f_scatter2(const int* __restrict__ src,
                                                  const int* __restrict__ dst,
                                                  const float2* __restrict__ g,
                                                  float* __restrict__ acc, int E) {
    int i = blockIdx.x * blockDim.x + threadIdx.x;
    if (i < E) {
        int s = src[i], d = dst[i];
        float2 gv = g[s];
        atomicAdd(&acc[2 * d], gv.x);
        atomicAdd(&acc[2 * d + 1], gv.y);
    }
}
__global__ __launch_bounds__(256) void f_out(const float* __restrict__ dinv,
                                             const float* __restrict__ b2,
                                             float* __restrict__ out, int N) {
    int i = blockIdx.x * blockDim.x + threadIdx.x;
    if (i < N) {
        float di = dinv[i];
        out[2 * i]     = fmaf(di, out[2 * i],     b2[0]);
        out[2 * i + 1] = fmaf(di, out[2 * i + 1], b2[1]);
    }
}

extern "C" void kernel_launch(void* const* d_in, const int* in_sizes, int n_in,
                              void* d_out, int out_size, void* d_ws, size_t ws_size,
                              hipStream_t stream) {
    const float* x  = (const float*)d_in[0];
    const int* ei   = (const int*)d_in[1];
    const int* src  = ei;
    const int* dst  = ei + NE;
    const float* W1 = (const float*)d_in[2];
    const float* b1 = (const float*)d_in[3];
    const float* W2 = (const float*)d_in[4];
    const float* b2 = (const float*)d_in[5];

    const int BT = 256;
    const int gridE = (NE + BT - 1) / BT;
    const int gridN = (NN + BT - 1) / BT;

    // workspace budget for the binned path (~15 MB)
    size_t need = 0;
    auto carve = [&](size_t bytes) { size_t o = need; need += (bytes + 255) & ~(size_t)255; return o; };
    size_t o_base  = carve(NB * 4);
    size_t o_total = carve(NB * 4);
    size_t o_H     = carve((size_t)NCH * NB * 4);
    size_t o_Off   = carve((size_t)NCH * NB * 4);
    size_t o_dinv  = carve((size_t)NN * 4);
    size_t o_p     = carve((size_t)NN * 4);
    size_t o_g     = carve((size_t)NN * 8);
    size_t o_bin   = carve((size_t)NE * 4);

    if (ws_size >= need) {
        char* ws = (char*)d_ws;
        unsigned* base  = (unsigned*)(ws + o_base);
        unsigned* total = (unsigned*)(ws + o_total);
        unsigned* H     = (unsigned*)(ws + o_H);
        unsigned* Off   = (unsigned*)(ws + o_Off);
        float*    dinv  = (float*)(ws + o_dinv);
        float*    p     = (float*)(ws + o_p);
        float2*   g     = (float2*)(ws + o_g);
        unsigned* binned= (unsigned*)(ws + o_bin);

        k_hist   <<<NCH, 256, 0, stream>>>(dst, H);
        k_colscan<<<(NB + 255) / 256, 256, 0, stream>>>(H, Off, total);
        k_base   <<<1, 512, 0, stream>>>(total, base);
        k_place  <<<NCH, 256, 0, stream>>>(src, dst, Off, base, binned);
        k_degnode<<<NB, 256, 0, stream>>>(binned, base, total, x, dinv, p);
        k_agg1   <<<NB, 256, 0, stream>>>(binned, base, total, dinv, p, W1, b1, W2, g);
        k_agg2   <<<NB, 256, 0, stream>>>(binned, base, total, dinv, g, b2, (float2*)d_out);
    } else {
        float* out = (float*)d_out;
        char* ws = (char*)d_ws;
        unsigned int* deg = (unsigned int*)ws;
        float* dinv = (float*)(ws + 1 * sizeof(float) * NN);
        float* p    = (float*)(ws + 2 * sizeof(float) * NN);
        float* t    = (float*)(ws + 3 * sizeof(float) * NN);
        float2* g   = (float2*)(ws + 4 * sizeof(float) * NN);

        hipMemsetAsync(deg, 0, NN * sizeof(unsigned int), stream);
        f_deg<<<gridE, BT, 0, stream>>>(dst, deg, NE);
        f_node1<<<gridN, BT, 0, stream>>>(x, deg, dinv, p, t, NN);
        f_scatter1<<<gridE, BT, 0, stream>>>(src, dst, p, t, NE);
        f_node2<<<gridN, BT, 0, stream>>>(dinv, t, W1, b1, W2, g, (float2*)out, NN);
        f_scatter2<<<gridE, BT, 0, stream>>>(src, dst, g, out, NE);
        f_out<<<gridN, BT, 0, stream>>>(dinv, b2, out, NN);
    }
}

// Round 4
// 215.725 us; speedup vs baseline: 3.2087x; 1.1437x over previous
//
#include <hip/hip_runtime.h>

#define NN 100000
#define NE 3200000
#define HC 16

#define BKT_BITS 7
#define BKT_NODES 128                 // nodes per bucket
#define NB 782                        // ceil(NN / 128)
#define CHUNK 4096
#define NCH 782                       // ceil(NE / CHUNK)

// ---------- pass 1: bucket-bin the edges (no global atomics) ----------

__global__ __launch_bounds__(256) void k_hist(const int* __restrict__ dst,
                                              unsigned short* __restrict__ H) {
    __shared__ unsigned h[NB];
    int tid = threadIdx.x;
    for (int j = tid; j < NB; j += 256) h[j] = 0;
    __syncthreads();
    int b0 = blockIdx.x * CHUNK;
    int e1 = min(b0 + CHUNK, NE);
    for (int i = b0 + tid; i < e1; i += 256)
        atomicAdd(&h[((unsigned)dst[i]) >> BKT_BITS], 1u);
    __syncthreads();
    unsigned short* row = H + (size_t)blockIdx.x * NB;
    for (int j = tid; j < NB; j += 256) row[j] = (unsigned short)h[j];
}

// one wave per bucket: exclusive running offsets across chunks, IN PLACE over H
__global__ __launch_bounds__(64) void k_colscan(unsigned short* __restrict__ HO,
                                                unsigned* __restrict__ total) {
    int b = blockIdx.x;
    int lane = threadIdx.x;
    unsigned run = 0;
    for (int c0 = 0; c0 < NCH; c0 += 64) {
        int c = c0 + lane;
        unsigned v = (c < NCH) ? (unsigned)HO[(size_t)c * NB + b] : 0u;
        unsigned sc = v;                       // inclusive wave scan
#pragma unroll
        for (int off = 1; off < 64; off <<= 1) {
            unsigned u = __shfl_up(sc, off, 64);
            if (lane >= off) sc += u;
        }
        if (c < NCH) HO[(size_t)c * NB + b] = (unsigned short)(run + sc - v);
        run += __shfl(sc, 63, 64);
    }
    if (lane == 0) total[b] = run;
}

__global__ __launch_bounds__(1024) void k_base(const unsigned* __restrict__ total,
                                               unsigned* __restrict__ base) {
    __shared__ unsigned s[1024];
    int t = threadIdx.x;
    unsigned v = (t < NB) ? total[t] : 0;
    s[t] = v;
    __syncthreads();
    for (int off = 1; off < 1024; off <<= 1) {
        unsigned u = (t >= off) ? s[t - off] : 0;
        __syncthreads();
        s[t] += u;
        __syncthreads();
    }
    if (t < NB) base[t] = s[t] - v;            // exclusive prefix
}

__global__ __launch_bounds__(256) void k_place(const int* __restrict__ src,
                                               const int* __restrict__ dst,
                                               const unsigned short* __restrict__ Off,
                                               const unsigned* __restrict__ base,
                                               unsigned* __restrict__ binned) {
    __shared__ unsigned cur[NB];
    int tid = threadIdx.x;
    const unsigned short* row = Off + (size_t)blockIdx.x * NB;
    for (int j = tid; j < NB; j += 256) cur[j] = base[j] + (unsigned)row[j];
    __syncthreads();
    int b0 = blockIdx.x * CHUNK;
    int e1 = min(b0 + CHUNK, NE);
    for (int i = b0 + tid; i < e1; i += 256) {
        unsigned d = (unsigned)dst[i];
        unsigned s = (unsigned)src[i];
        unsigned bk = d >> BKT_BITS;
        unsigned pos = atomicAdd(&cur[bk], 1u);           // LDS atomic only
        binned[pos] = (s << BKT_BITS) | (d & (BKT_NODES - 1));
    }
}

// ---------- pass 2: per-bucket LDS aggregation ----------

__global__ __launch_bounds__(256) void k_degnode(const unsigned* __restrict__ binned,
                                                 const unsigned* __restrict__ base,
                                                 const unsigned* __restrict__ total,
                                                 const float* __restrict__ x,
                                                 float* __restrict__ dinv,
                                                 float* __restrict__ p) {
    __shared__ unsigned cnt[BKT_NODES];
    int tid = threadIdx.x;
    if (tid < BKT_NODES) cnt[tid] = 0;
    __syncthreads();
    unsigned s0 = base[blockIdx.x], c0 = total[blockIdx.x];
    for (unsigned i = tid; i < c0; i += 256)
        atomicAdd(&cnt[binned[s0 + i] & (BKT_NODES - 1)], 1u);
    __syncthreads();
    int node = blockIdx.x * BKT_NODES + tid;
    if (tid < BKT_NODES && node < NN) {
        float di = rsqrtf((float)(cnt[tid] + 1u));        // +1 self-loop
        dinv[node] = di;
        p[node] = di * x[node];
    }
}

__global__ __launch_bounds__(256) void k_agg1(const unsigned* __restrict__ binned,
                                              const unsigned* __restrict__ base,
                                              const unsigned* __restrict__ total,
                                              const float* __restrict__ dinv,
                                              const float* __restrict__ p,
                                              const float* __restrict__ W1,
                                              const float* __restrict__ b1,
                                              const float* __restrict__ W2,
                                              float2* __restrict__ g) {
    __shared__ float acc[BKT_NODES];
    int tid = threadIdx.x;
    if (tid < BKT_NODES) acc[tid] = 0.f;
    __syncthreads();
    unsigned s0 = base[blockIdx.x], c0 = total[blockIdx.x];
    for (unsigned i = tid; i < c0; i += 256) {
        unsigned e = binned[s0 + i];
        atomicAdd(&acc[e & (BKT_NODES - 1)], p[e >> BKT_BITS]);
    }
    __syncthreads();
    int node = blockIdx.x * BKT_NODES + tid;
    if (tid < BKT_NODES && node < NN) {
        float di = dinv[node];
        float s = di * (acc[tid] + p[node]);              // + self-loop
        float g0 = 0.f, g1 = 0.f;
#pragma unroll
        for (int c = 0; c < HC; ++c) {
            float h = fmaxf(fmaf(s, W1[c], b1[c]), 0.f);
            g0 = fmaf(h, W2[2 * c], g0);
            g1 = fmaf(h, W2[2 * c + 1], g1);
        }
        g[node] = make_float2(di * g0, di * g1);
    }
}

__global__ __launch_bounds__(256) void k_agg2(const unsigned* __restrict__ binned,
                                              const unsigned* __restrict__ base,
                                              const unsigned* __restrict__ total,
                                              const float* __restrict__ dinv,
                                              const float2* __restrict__ g,
                                              const float* __restrict__ b2,
                                              float2* __restrict__ out) {
    __shared__ float ax[BKT_NODES];
    __shared__ float ay[BKT_NODES];
    int tid = threadIdx.x;
    if (tid < BKT_NODES) { ax[tid] = 0.f; ay[tid] = 0.f; }
    __syncthreads();
    unsigned s0 = base[blockIdx.x], c0 = total[blockIdx.x];
    for (unsigned i = tid; i < c0; i += 256) {
        unsigned e = binned[s0 + i];
        float2 v = g[e >> BKT_BITS];
        unsigned l = e & (BKT_NODES - 1);
        atomicAdd(&ax[l], v.x);
        atomicAdd(&ay[l], v.y);
    }
    __syncthreads();
    int node = blockIdx.x * BKT_NODES + tid;
    if (tid < BKT_NODES && node < NN) {
        float di = dinv[node];
        float2 me = g[node];
        out[node] = make_float2(fmaf(di, ax[tid] + me.x, b2[0]),
                                fmaf(di, ay[tid] + me.y, b2[1]));
    }
}

// ---------- fallback: round-1 atomic-scatter path (small ws) ----------

__global__ __launch_bounds__(256) void f_deg(const int* __restrict__ dst,
                                             unsigned int* __restrict__ deg, int E) {
    int i = blockIdx.x * blockDim.x + threadIdx.x;
    if (i < E) atomicAdd(&deg[dst[i]], 1u);
}
__global__ __launch_bounds__(256) void f_node1(const float* __restrict__ x,
                                               const unsigned int* __restrict__ deg,
                                               float* __restrict__ dinv, float* __restrict__ p,
                                               float* __restrict__ t, int N) {
    int i = blockIdx.x * blockDim.x + threadIdx.x;
    if (i < N) {
        float di = rsqrtf((float)(deg[i] + 1u));
        dinv[i] = di; float pi = di * x[i]; p[i] = pi; t[i] = pi;
    }
}
__global__ __launch_bounds__(256) void f_scatter1(const int* __restrict__ src,
                                                  const int* __restrict__ dst,
                                                  const float* __restrict__ p,
                                                  float* __restrict__ t, int E) {
    int i = blockIdx.x * blockDim.x + threadIdx.x;
    if (i < E) atomicAdd(&t[dst[i]], p[src[i]]);
}
__global__ __launch_bounds__(256) void f_node2(const float* __restrict__ dinv,
                                               const float* __restrict__ t,
                                               const float* __restrict__ W1,
                                               const float* __restrict__ b1,
                                               const float* __restrict__ W2,
                                               float2* __restrict__ g,
                                               float2* __restrict__ acc, int N) {
    int i = blockIdx.x * blockDim.x + threadIdx.x;
    if (i < N) {
        float di = dinv[i]; float s = di * t[i];
        float g0 = 0.f, g1 = 0.f;
#pragma unroll
        for (int c = 0; c < HC; ++c) {
            float h = fmaxf(fmaf(s, W1[c], b1[c]), 0.f);
            g0 = fmaf(h, W2[2 * c], g0); g1 = fmaf(h, W2[2 * c + 1], g1);
        }
        float2 gv = make_float2(di * g0, di * g1);
        g[i] = gv; acc[i] = gv;
    }
}
__global__ __launch_bounds__(256) void f_scatter2(const int* __restrict__ src,
                                                  const int* __restrict__ dst,
                                                  const float2* __restrict__ g,
                                                  float* __restrict__ acc, int E) {
    int i = blockIdx.x * blockDim.x + threadIdx.x;
    if (i < E) {
        int s = src[i], d = dst[i];
        float2 gv = g[s];
        atomicAdd(&acc[2 * d], gv.x);
        atomicAdd(&acc[2 * d + 1], gv.y);
    }
}
__global__ __launch_bounds__(256) void f_out(const float* __restrict__ dinv,
                                             const float* __restrict__ b2,
                                             float* __restrict__ out, int N) {
    int i = blockIdx.x * blockDim.x + threadIdx.x;
    if (i < N) {
        float di = dinv[i];
        out[2 * i]     = fmaf(di, out[2 * i],     b2[0]);
        out[2 * i + 1] = fmaf(di, out[2 * i + 1], b2[1]);
    }
}

extern "C" void kernel_launch(void* const* d_in, const int* in_sizes, int n_in,
                              void* d_out, int out_size, void* d_ws, size_t ws_size,
                              hipStream_t stream) {
    const float* x  = (const float*)d_in[0];
    const int* ei   = (const int*)d_in[1];
    const int* src  = ei;
    const int* dst  = ei + NE;
    const float* W1 = (const float*)d_in[2];
    const float* b1 = (const float*)d_in[3];
    const float* W2 = (const float*)d_in[4];
    const float* b2 = (const float*)d_in[5];

    const int BT = 256;
    const int gridE = (NE + BT - 1) / BT;
    const int gridN = (NN + BT - 1) / BT;

    // workspace carve-up. The HO region (u16 hist/offsets, scanned in place)
    // is reused for dinv+p after k_place has consumed it (stream-ordered).
    size_t need = 0;
    auto carve = [&](size_t bytes) { size_t o = need; need += (bytes + 255) & ~(size_t)255; return o; };
    size_t ho_bytes   = (size_t)NCH * NB * 2;               // 1.22 MB
    size_t np_bytes   = 2 * (((size_t)NN * 4 + 255) & ~(size_t)255); // dinv + p
    size_t o_base  = carve(NB * 4);
    size_t o_total = carve(NB * 4);
    size_t o_HO    = carve(ho_bytes > np_bytes ? ho_bytes : np_bytes);
    size_t o_g     = carve((size_t)NN * 8);
    size_t o_bin   = carve((size_t)NE * 4);

    if (ws_size >= need) {
        char* ws = (char*)d_ws;
        unsigned* base   = (unsigned*)(ws + o_base);
        unsigned* total  = (unsigned*)(ws + o_total);
        unsigned short* HO = (unsigned short*)(ws + o_HO);
        float*    dinv   = (float*)(ws + o_HO);             // overlays HO (post-place)
        float*    p      = (float*)(ws + o_HO + (((size_t)NN * 4 + 255) & ~(size_t)255));
        float2*   g      = (float2*)(ws + o_g);
        unsigned* binned = (unsigned*)(ws + o_bin);

        k_hist   <<<NCH, 256, 0, stream>>>(dst, HO);
        k_colscan<<<NB, 64, 0, stream>>>(HO, total);
        k_base   <<<1, 1024, 0, stream>>>(total, base);
        k_place  <<<NCH, 256, 0, stream>>>(src, dst, HO, base, binned);
        k_degnode<<<NB, 256, 0, stream>>>(binned, base, total, x, dinv, p);
        k_agg1   <<<NB, 256, 0, stream>>>(binned, base, total, dinv, p, W1, b1, W2, g);
        k_agg2   <<<NB, 256, 0, stream>>>(binned, base, total, dinv, g, b2, (float2*)d_out);
    } else {
        float* out = (float*)d_out;
        char* ws = (char*)d_ws;
        unsigned int* deg = (unsigned int*)ws;
        float* dinv = (float*)(ws + 1 * sizeof(float) * NN);
        float* p    = (float*)(ws + 2 * sizeof(float) * NN);
        float* t    = (float*)(ws + 3 * sizeof(float) * NN);
        float2* g   = (float2*)(ws + 4 * sizeof(float) * NN);

        hipMemsetAsync(deg, 0, NN * sizeof(unsigned int), stream);
        f_deg<<<gridE, BT, 0, stream>>>(dst, deg, NE);
        f_node1<<<gridN, BT, 0, stream>>>(x, deg, dinv, p, t, NN);
        f_scatter1<<<gridE, BT, 0, stream>>>(src, dst, p, t, NE);
        f_node2<<<gridN, BT, 0, stream>>>(dinv, t, W1, b1, W2, g, (float2*)out, NN);
        f_scatter2<<<gridE, BT, 0, stream>>>(src, dst, g, out, NE);
        f_out<<<gridN, BT, 0, stream>>>(dinv, b2, out, NN);
    }
}